// Round 11
// baseline (79.809 us; speedup 1.0000x reference)
//
#include <hip/hip_runtime.h>
#include <hip/hip_bf16.h>
#include <cstdint>
#include <cstddef>

namespace {

constexpr int B = 4, N = 128, C = 256, E = 128, O = 128, CH = 8;
constexpr float NEGV = -1.0e9f;

// ---- workspace layout (in float units) ----
constexpr size_t SZ_TE_F  = (size_t)B * N * N * CH / 2;   // bf16 tensors
constexpr size_t OFF_TE1T = 0;                             // bf16 [b][j][i][c]
constexpr size_t OFF_TE2  = OFF_TE1T + SZ_TE_F;            // bf16 [b][i][k][c]
constexpr size_t OFF_TE3  = OFF_TE2 + SZ_TE_F;             // bf16 [b][j][k][c]
constexpr size_t OFF_M1   = OFF_TE3 + SZ_TE_F;             // f32 m1+mg [b][n][o]
constexpr size_t OFF_M2   = OFF_M1 + (size_t)B * N * O;
constexpr size_t OFF_ZU1  = OFF_M2 + (size_t)B * N * O;    // f32 [b][n][o]
constexpr size_t OFF_T1   = OFF_ZU1 + (size_t)B * N * O;   // f32 [b][n][c]
constexpr size_t OFF_T2   = OFF_T1 + (size_t)B * N * CH;
constexpr size_t OFF_T3   = OFF_T2 + (size_t)B * N * CH;
constexpr size_t OFF_TG   = OFF_T3 + (size_t)B * N * CH;   // f32 [b][c]
constexpr size_t OFF_WT   = OFF_TG + (size_t)B * CH;       // 3 x bf16[O][E]
constexpr size_t OFF_PART = OFF_WT + (size_t)3 * O * E / 2;  // f32 [b][j][4][o]

typedef __attribute__((ext_vector_type(4))) float f32x4;
typedef __attribute__((ext_vector_type(8))) short bf16x8;
typedef __attribute__((ext_vector_type(8))) unsigned short u16x8;

__device__ __forceinline__ unsigned short f2b(float f) {
  unsigned u = __float_as_uint(f);
  u = (u + 0x7fffu + ((u >> 16) & 1u)) >> 16;
  return (unsigned short)u;
}
__device__ __forceinline__ float b2f(unsigned short u) {
  return __uint_as_float((unsigned)u << 16);
}
__device__ __forceinline__ ushort4 f2b4(float4 v) {
  ushort4 pk;
  pk.x = f2b(v.x); pk.y = f2b(v.y); pk.z = f2b(v.z); pk.w = f2b(v.w);
  return pk;
}

} // namespace

// ---------------------------------------------------------------------------
// Kernel A (prep): fused te-MFMA [0,512) + pre [512,1024) + wprep [1024,1027)
// te branch: barrier-free j-loop, e fragments direct from global.
// ---------------------------------------------------------------------------
__global__ __launch_bounds__(256) void k_prep(
    const float* __restrict__ z, const float* __restrict__ g,
    const float* __restrict__ e,
    const float* __restrict__ Wt1, const float* __restrict__ Wt2,
    const float* __restrict__ Wt3, const float* __restrict__ Wtg,
    const float* __restrict__ Wm1, const float* __restrict__ Wm2,
    const float* __restrict__ Wmg, const float* __restrict__ WU1,
    const float* __restrict__ Wte1, const float* __restrict__ Wte2,
    const float* __restrict__ Wte3,
    const float* __restrict__ Wme, const float* __restrict__ Wmlp1,
    const float* __restrict__ Wmlp2, float* __restrict__ ws) {
  __shared__ __align__(16) char smem[17408];
  const int blk = blockIdx.x;
  const int t = threadIdx.x;

  if (blk < 512) {
    // ============ te branch (MFMA; no e staging; no inner barriers) ========
    unsigned short* wpack = (unsigned short*)(smem);            // [32][136]
    unsigned short* outl  = (unsigned short*)(smem + 8704);     // [128][32]
    unsigned short* te1T = (unsigned short*)(ws + OFF_TE1T);
    unsigned short* te2  = (unsigned short*)(ws + OFF_TE2);
    unsigned short* te3  = (unsigned short*)(ws + OFF_TE3);
    const int b = blk >> 7, i = blk & 127;

    // stage packed transposed weights: wpack[m*8+c][k] = Wte_m[k][c]
    for (int x = t; x < 3072; x += 256) {
      const int m = x >> 10, rem = x & 1023, k = rem >> 3, c = rem & 7;
      const float* W = (m == 0) ? Wte1 : ((m == 1) ? Wte2 : Wte3);
      const int row = m * 8 + c;
      wpack[row * 136 + k] = f2b(W[rem]);
    }
    for (int x = t; x < 1024; x += 256) {
      const int row = 24 + (x >> 7), col = x & 127;
      wpack[row * 136 + col] = 0;
    }
    __syncthreads();

    const float* erow = e + ((size_t)(b * N) + i) * N * E;
    const int lane = t & 63, wid = t >> 6;
    const int li = lane & 15, lk8 = (lane >> 4) * 8, lq4 = (lane >> 4) * 4;
    const int jt = wid & 1, ct = wid >> 1;
    const int c0 = ct * 16 + lq4;

    // weight fragments -> regs once
    bf16x8 wf[4];
#pragma unroll
    for (int kt = 0; kt < 4; ++kt) {
      const int rw = ct * 16 + li;
      wf[kt] = *reinterpret_cast<const bf16x8*>(&wpack[rw * 136 + kt * 32 + lk8]);
    }

    // 4 independent j-steps, zero barriers
#pragma unroll 2
    for (int step = 0; step < 4; ++step) {
      const int jrow = step * 32 + jt * 16 + li;
      const float* er = erow + (size_t)jrow * E;
      float4 v[4][2];
#pragma unroll
      for (int kt = 0; kt < 4; ++kt) {
        v[kt][0] = *reinterpret_cast<const float4*>(&er[kt * 32 + lk8]);
        v[kt][1] = *reinterpret_cast<const float4*>(&er[kt * 32 + lk8 + 4]);
      }
      f32x4 acc = {0.f, 0.f, 0.f, 0.f};
#pragma unroll
      for (int kt = 0; kt < 4; ++kt) {
        u16x8 af;
        af[0] = f2b(v[kt][0].x); af[1] = f2b(v[kt][0].y);
        af[2] = f2b(v[kt][0].z); af[3] = f2b(v[kt][0].w);
        af[4] = f2b(v[kt][1].x); af[5] = f2b(v[kt][1].y);
        af[6] = f2b(v[kt][1].z); af[7] = f2b(v[kt][1].w);
        acc = __builtin_amdgcn_mfma_f32_16x16x32_bf16(
            wf[kt], (bf16x8)af, acc, 0, 0, 0);
      }
      if (c0 < 24) {
        ushort4 pk;
        pk.x = f2b(acc[0]); pk.y = f2b(acc[1]);
        pk.z = f2b(acc[2]); pk.w = f2b(acc[3]);
        *reinterpret_cast<ushort4*>(&outl[jrow * 32 + c0]) = pk;
      }
    }
    __syncthreads();
    for (int x = t; x < 384; x += 256) {
      const int m = x >> 7, j = x & 127;
      const u16x8 v = *reinterpret_cast<const u16x8*>(&outl[j * 32 + m * 8]);
      if (m == 0)
        *reinterpret_cast<u16x8*>(&te1T[(((size_t)(b * N) + j) * N + i) * CH]) = v;
      else if (m == 1)
        *reinterpret_cast<u16x8*>(&te2[(((size_t)(b * N) + i) * N + j) * CH]) = v;
      else
        *reinterpret_cast<u16x8*>(&te3[(((size_t)(b * N) + i) * N + j) * CH]) = v;
    }
  } else if (blk < 1024) {
    // ===================== pre branch =====================
    float* zrow = (float*)(smem);
    float* grow = (float*)(smem + 1024);
    const int bn = blk - 512;
    const int b = bn >> 7, n = bn & 127;

    for (int k = t; k < C; k += 256) zrow[k] = z[((size_t)(b * N) + n) * C + k];
    if (t < C / 2) grow[t] = g[(size_t)b * (C / 2) + t];
    __syncthreads();

    {
      const int o = t & 127;
      const float* W = (t < 128) ? Wm1 : Wm2;
      float acc = 0.f;
#pragma unroll 16
      for (int k = 0; k < C; ++k) acc += zrow[k] * W[(size_t)k * O + o];
      if (t < 128) {
        float mgacc = 0.f;
#pragma unroll 8
        for (int k = 0; k < C / 2; ++k) mgacc += grow[k] * Wmg[(size_t)k * O + o];
        acc += mgacc;
        ws[OFF_M1 + ((size_t)(b * N) + n) * O + o] = acc;
      } else {
        ws[OFF_M2 + ((size_t)(b * N) + n) * O + o] = acc;
      }
    }
    if (t < 128) {
      float acc = 0.f;
#pragma unroll 16
      for (int k = 0; k < C; ++k) acc += zrow[k] * WU1[(size_t)k * O + t];
      ws[OFF_ZU1 + ((size_t)(b * N) + n) * O + t] = acc;
    } else if (t < 152) {
      const int idx = t - 128;
      const int which = idx >> 3, c = idx & 7;
      const float* W = (which == 0) ? Wt1 : ((which == 1) ? Wt2 : Wt3);
      float acc = 0.f;
#pragma unroll 8
      for (int k = 0; k < C; ++k) acc += zrow[k] * W[(size_t)k * CH + c];
      const size_t off = (which == 0) ? OFF_T1 : ((which == 1) ? OFF_T2 : OFF_T3);
      ws[off + ((size_t)(b * N) + n) * CH + c] = acc;
    }
    if (n == 0 && t >= 152 && t < 160) {
      const int c = t - 152;
      float acc = 0.f;
      for (int k = 0; k < C / 2; ++k) acc += grow[k] * Wtg[(size_t)k * CH + c];
      ws[OFF_TG + (size_t)b * CH + c] = acc;
    }
  } else {
    // ===================== wprep branch =====================
    const int which = blk - 1024;
    const float* W = (which == 0) ? Wme : ((which == 1) ? Wmlp1 : Wmlp2);
    unsigned short* dst = (unsigned short*)(ws + OFF_WT) + (size_t)which * O * E;
    for (int x = t; x < O * E; x += 256) {
      const int o = x >> 7, k = x & 127;
      dst[x] = f2b(W[(size_t)k * O + o]);
    }
  }
}

// ---------------------------------------------------------------------------
// Kernel B (main), 512 threads:
//  blocks [0,256): msgs weight-stationary (FULL staging fix: 512 threads x 2
//  segments cover all 32x128 elements of the act tile)
//  blocks [256,512): tri: (b, kh, jt) -> 64 k-rows x 4 j's
// ---------------------------------------------------------------------------
__global__ __launch_bounds__(512) void k_main(
    const float* __restrict__ e, const void* __restrict__ msk,
    const float* __restrict__ WU3, const float* __restrict__ ws_c,
    float* __restrict__ ws, float* __restrict__ out_tri) {
  __shared__ __align__(16) char smem[33856];
  const int blk = blockIdx.x;
  const int t = threadIdx.x;

  if (blk < 256) {
    // ============== msgs branch ==============
    unsigned short* act0 = (unsigned short*)(smem);          // [32][136]
    unsigned short* act1 = (unsigned short*)(smem + 8704);   // [32][136]
    float* m2s = (float*)(smem + 17408);                     // [32][128]
    int* fmtp = (int*)(smem + 33792);
    const int jg = blk & 15, ig = (blk >> 4) & 3, b = blk >> 6;
    const int j0 = jg * 8, i0g = ig * 32;
    constexpr int LDK = 136;

    const int lane = t & 63, wid = t >> 6;  // wid = o-tile 0..7
    const int li = lane & 15;
    const int lk8 = (lane >> 4) * 8;
    const int lq4 = (lane >> 4) * 4;

    // mask dtype sniff
    if (t < 64) {
      const unsigned w = ((const unsigned*)msk)[t];
      const float f = __uint_as_float(w);
      const unsigned long long bad_int = __ballot(w > 1u);
      const unsigned long long bad_flt = __ballot(!(f == 0.f || f == 1.f));
      if (t == 0) *fmtp = (bad_int == 0ull) ? 0 : ((bad_flt == 0ull) ? 2 : 1);
    }

    // weight fragments -> registers (once per block)
    const unsigned short* wts = (const unsigned short*)(ws_c + OFF_WT);
    bf16x8 wf0[4], wf1[4], wf2[4];
#pragma unroll
    for (int kt = 0; kt < 4; ++kt) {
      const size_t off = (size_t)(wid * 16 + li) * E + kt * 32 + lk8;
      wf0[kt] = *reinterpret_cast<const bf16x8*>(&wts[off]);
      wf1[kt] = *reinterpret_cast<const bf16x8*>(&wts[(size_t)O * E + off]);
      wf2[kt] = *reinterpret_cast<const bf16x8*>(&wts[(size_t)2 * O * E + off]);
    }
    // m2 tile (j-invariant) -> LDS once
    for (int x = t; x < 32 * O; x += 512)
      m2s[x] = ws_c[OFF_M2 + ((size_t)(b * N) + i0g + (x >> 7)) * O + (x & 127)];
    __syncthreads();
    const int fmt = *fmtp;

    const int iA = i0g + li, iB = i0g + 16 + li;
    // staging roles: all 512 threads, 2 (row,seg) slots each — FULL coverage
    const int prow0 = t >> 5;          // rows 0..15
    const int prow1 = 16 + (t >> 5);   // rows 16..31
    const int pseg = t & 31;           // segs 0..31 (x4 floats = cols 0..127)

    // ---- initial prefetch + stage for j0 ----
    float4 ev0, ev1;
    ev0 = *reinterpret_cast<const float4*>(
        &e[(((size_t)(b * N) + i0g + prow0) * N + j0) * E + pseg * 4]);
    ev1 = *reinterpret_cast<const float4*>(
        &e[(((size_t)(b * N) + i0g + prow1) * N + j0) * E + pseg * 4]);
    float4 m1c = *reinterpret_cast<const float4*>(
        &ws_c[OFF_M1 + ((size_t)(b * N) + j0) * O + wid * 16 + lq4]);
    int mkAc, mkBc;
    {
      const size_t ia = ((size_t)(b * N) + iA) * N + j0;
      const size_t ib = ((size_t)(b * N) + iB) * N + j0;
      if (fmt == 0) { mkAc = ((const int*)msk)[ia] != 0; mkBc = ((const int*)msk)[ib] != 0; }
      else if (fmt == 1) { mkAc = ((const unsigned char*)msk)[ia] != 0; mkBc = ((const unsigned char*)msk)[ib] != 0; }
      else { mkAc = ((const float*)msk)[ia] != 0.f; mkBc = ((const float*)msk)[ib] != 0.f; }
    }
    *reinterpret_cast<ushort4*>(&act0[prow0 * LDK + pseg * 4]) = f2b4(ev0);
    *reinterpret_cast<ushort4*>(&act0[prow1 * LDK + pseg * 4]) = f2b4(ev1);
    __syncthreads();

    unsigned short* actc = act0;
    unsigned short* actn = act1;
    const int o0 = wid * 16 + lq4;

    for (int jj = 0; jj < 8; ++jj) {
      const int j = j0 + jj;
      const int jn = (jj < 7) ? j + 1 : j;

      bf16x8 af[2][4];
      f32x4 acc[2];

      // ===== layer 1 =====
#pragma unroll
      for (int it = 0; it < 2; ++it)
#pragma unroll
        for (int kt = 0; kt < 4; ++kt)
          af[it][kt] = *reinterpret_cast<const bf16x8*>(
              &actc[(it * 16 + li) * LDK + kt * 32 + lk8]);
      // prefetch next j (T14: issue early)
      ev0 = *reinterpret_cast<const float4*>(
          &e[(((size_t)(b * N) + i0g + prow0) * N + jn) * E + pseg * 4]);
      ev1 = *reinterpret_cast<const float4*>(
          &e[(((size_t)(b * N) + i0g + prow1) * N + jn) * E + pseg * 4]);
      float4 m1n = *reinterpret_cast<const float4*>(
          &ws_c[OFF_M1 + ((size_t)(b * N) + jn) * O + o0]);
      int mkAn, mkBn;
      {
        const size_t ia = ((size_t)(b * N) + iA) * N + jn;
        const size_t ib = ((size_t)(b * N) + iB) * N + jn;
        if (fmt == 0) { mkAn = ((const int*)msk)[ia] != 0; mkBn = ((const int*)msk)[ib] != 0; }
        else if (fmt == 1) { mkAn = ((const unsigned char*)msk)[ia] != 0; mkBn = ((const unsigned char*)msk)[ib] != 0; }
        else { mkAn = ((const float*)msk)[ia] != 0.f; mkBn = ((const float*)msk)[ib] != 0.f; }
      }
      acc[0] = (f32x4){0.f, 0.f, 0.f, 0.f};
      acc[1] = (f32x4){0.f, 0.f, 0.f, 0.f};
#pragma unroll
      for (int kt = 0; kt < 4; ++kt) {
        acc[0] = __builtin_amdgcn_mfma_f32_16x16x32_bf16(wf0[kt], af[0][kt], acc[0], 0, 0, 0);
        acc[1] = __builtin_amdgcn_mfma_f32_16x16x32_bf16(wf0[kt], af[1][kt], acc[1], 0, 0, 0);
      }
      __syncthreads();
      // writeback 1: relu(mask*me + m2 + m1')
#pragma unroll
      for (int it = 0; it < 2; ++it) {
        const int i = it * 16 + li;
        const float mk = (it ? mkBc : mkAc) ? 1.f : 0.f;
        const float4 m2v = *reinterpret_cast<const float4*>(&m2s[i * O + o0]);
        ushort4 pk;
        pk.x = f2b(fmaxf(acc[it][0] * mk + m2v.x + m1c.x, 0.f));
        pk.y = f2b(fmaxf(acc[it][1] * mk + m2v.y + m1c.y, 0.f));
        pk.z = f2b(fmaxf(acc[it][2] * mk + m2v.z + m1c.z, 0.f));
        pk.w = f2b(fmaxf(acc[it][3] * mk + m2v.w + m1c.w, 0.f));
        *reinterpret_cast<ushort4*>(&actc[i * LDK + o0]) = pk;
      }
      __syncthreads();

      // ===== layer 2 =====
#pragma unroll
      for (int it = 0; it < 2; ++it)
#pragma unroll
        for (int kt = 0; kt < 4; ++kt)
          af[it][kt] = *reinterpret_cast<const bf16x8*>(
              &actc[(it * 16 + li) * LDK + kt * 32 + lk8]);
      acc[0] = (f32x4){0.f, 0.f, 0.f, 0.f};
      acc[1] = (f32x4){0.f, 0.f, 0.f, 0.f};
#pragma unroll
      for (int kt = 0; kt < 4; ++kt) {
        acc[0] = __builtin_amdgcn_mfma_f32_16x16x32_bf16(wf1[kt], af[0][kt], acc[0], 0, 0, 0);
        acc[1] = __builtin_amdgcn_mfma_f32_16x16x32_bf16(wf1[kt], af[1][kt], acc[1], 0, 0, 0);
      }
      __syncthreads();
#pragma unroll
      for (int it = 0; it < 2; ++it) {
        const int i = it * 16 + li;
        ushort4 pk;
        pk.x = f2b(fmaxf(acc[it][0], 0.f));
        pk.y = f2b(fmaxf(acc[it][1], 0.f));
        pk.z = f2b(fmaxf(acc[it][2], 0.f));
        pk.w = f2b(fmaxf(acc[it][3], 0.f));
        *reinterpret_cast<ushort4*>(&actc[i * LDK + o0]) = pk;
      }
      __syncthreads();

      // ===== layer 3 =====
#pragma unroll
      for (int it = 0; it < 2; ++it)
#pragma unroll
        for (int kt = 0; kt < 4; ++kt)
          af[it][kt] = *reinterpret_cast<const bf16x8*>(
              &actc[(it * 16 + li) * LDK + kt * 32 + lk8]);
      acc[0] = (f32x4){0.f, 0.f, 0.f, 0.f};
      acc[1] = (f32x4){0.f, 0.f, 0.f, 0.f};
#pragma unroll
      for (int kt = 0; kt < 4; ++kt) {
        acc[0] = __builtin_amdgcn_mfma_f32_16x16x32_bf16(wf2[kt], af[0][kt], acc[0], 0, 0, 0);
        acc[1] = __builtin_amdgcn_mfma_f32_16x16x32_bf16(wf2[kt], af[1][kt], acc[1], 0, 0, 0);
      }
      // stage next j into the other buffer (T14: write late) — FULL coverage
      *reinterpret_cast<ushort4*>(&actn[prow0 * LDK + pseg * 4]) = f2b4(ev0);
      *reinterpret_cast<ushort4*>(&actn[prow1 * LDK + pseg * 4]) = f2b4(ev1);
      // masked max over 32 rows + partial write
      {
        float v0 = fmaxf(mkAc ? acc[0][0] : NEGV, mkBc ? acc[1][0] : NEGV);
        float v1 = fmaxf(mkAc ? acc[0][1] : NEGV, mkBc ? acc[1][1] : NEGV);
        float v2 = fmaxf(mkAc ? acc[0][2] : NEGV, mkBc ? acc[1][2] : NEGV);
        float v3 = fmaxf(mkAc ? acc[0][3] : NEGV, mkBc ? acc[1][3] : NEGV);
#pragma unroll
        for (int off = 1; off < 16; off <<= 1) {
          v0 = fmaxf(v0, __shfl_xor(v0, off));
          v1 = fmaxf(v1, __shfl_xor(v1, off));
          v2 = fmaxf(v2, __shfl_xor(v2, off));
          v3 = fmaxf(v3, __shfl_xor(v3, off));
        }
        if (li == 0) {
          float* part = ws + OFF_PART + (((size_t)(b * N) + j) * 4 + ig) * O;
          *reinterpret_cast<float4*>(&part[o0]) = make_float4(v0, v1, v2, v3);
        }
      }
      __syncthreads();
      // rotate
      unsigned short* tmp = actc; actc = actn; actn = tmp;
      m1c = m1n; mkAc = mkAn; mkBc = mkBn;
    }
  } else {
    // ============== tri branch: (b, kh, jt->4 j's), 512 threads ==============
    float* A4   = (float*)(smem);            // [4][128][8] f32
    float* wu3  = (float*)(smem + 16384);    // [8][128] f32
    float* trif = (float*)(smem + 20480);    // [4][64][8] f32
    float* t2j4 = (float*)(smem + 28672);    // [4][8]
    float* tgb  = (float*)(smem + 28800);    // [8]
    const int blk2 = blk - 256;
    const int kh = blk2 & 1, jt = (blk2 >> 1) & 31, b = blk2 >> 6;
    const int j0 = jt * 4;

    const unsigned short* te1T = (const unsigned short*)(ws_c + OFF_TE1T);
    const unsigned short* te2p =
        (const unsigned short*)(ws_c + OFF_TE2) + (size_t)b * N * N * CH;
    const unsigned short* te3p = (const unsigned short*)(ws_c + OFF_TE3);
    const float* t1p = ws_c + OFF_T1 + (size_t)b * N * CH;
    const float* t3p = ws_c + OFF_T3 + (size_t)b * N * CH;

    {
      const int idx8 = t * 8;
      const int jj = idx8 >> 10, i = (idx8 & 1023) >> 3;
      const u16x8 tv = *reinterpret_cast<const u16x8*>(
          &te1T[((size_t)(b * N) + j0 + jj) * N * CH + i * 8]);
      const float4 t1a = *reinterpret_cast<const float4*>(&t1p[i * 8]);
      const float4 t1b = *reinterpret_cast<const float4*>(&t1p[i * 8 + 4]);
      float4 av0, av1;
      av0.x = b2f(tv[0]) + t1a.x; av0.y = b2f(tv[1]) + t1a.y;
      av0.z = b2f(tv[2]) + t1a.z; av0.w = b2f(tv[3]) + t1a.w;
      av1.x = b2f(tv[4]) + t1b.x; av1.y = b2f(tv[5]) + t1b.y;
      av1.z = b2f(tv[6]) + t1b.z; av1.w = b2f(tv[7]) + t1b.w;
      *reinterpret_cast<float4*>(&A4[idx8]) = av0;
      *reinterpret_cast<float4*>(&A4[idx8 + 4]) = av1;
    }
    if (t < 256)
      *reinterpret_cast<float4*>(&wu3[t * 4]) =
          *reinterpret_cast<const float4*>(&WU3[t * 4]);
    if (t < 32)
      t2j4[t] = ws_c[OFF_T2 + ((size_t)(b * N) + j0 + (t >> 3)) * CH + (t & 7)];
    if (t < 8) tgb[t] = ws_c[OFF_TG + (size_t)b * CH + t];
    __syncthreads();

    const int io = t & 7, kl = t >> 3;  // kl 0..63
    const int kg = kh * 64 + kl;
    const size_t kbase = (size_t)kg * CH;
    float core[4][8];
#pragma unroll
    for (int jj = 0; jj < 4; ++jj)
#pragma unroll
      for (int c = 0; c < 8; ++c) core[jj][c] = -3.0e38f;

#pragma unroll 2
    for (int i0 = 0; i0 < N; i0 += 8) {
      const int i = i0 + io;
      const u16x8 rv =
          *reinterpret_cast<const u16x8*>(&te2p[(size_t)i * N * CH + kbase]);
      float r[8];
#pragma unroll
      for (int c = 0; c < 8; ++c) r[c] = b2f(rv[c]);
#pragma unroll
      for (int jj = 0; jj < 4; ++jj) {
        const float4 a0 = *reinterpret_cast<const float4*>(&A4[jj * 1024 + i * 8]);
        const float4 a1 = *reinterpret_cast<const float4*>(&A4[jj * 1024 + i * 8 + 4]);
        core[jj][0] = fmaxf(core[jj][0], a0.x + r[0]);
        core[jj][1] = fmaxf(core[jj][1], a0.y + r[1]);
        core[jj][2] = fmaxf(core[jj][2], a0.z + r[2]);
        core[jj][3] = fmaxf(core[jj][3], a0.w + r[3]);
        core[jj][4] = fmaxf(core[jj][4], a1.x + r[4]);
        core[jj][5] = fmaxf(core[jj][5], a1.y + r[5]);
        core[jj][6] = fmaxf(core[jj][6], a1.z + r[6]);
        core[jj][7] = fmaxf(core[jj][7], a1.w + r[7]);
      }
    }
#pragma unroll
    for (int jj = 0; jj < 4; ++jj)
#pragma unroll
      for (int c = 0; c < 8; ++c) {
        core[jj][c] = fmaxf(core[jj][c], __shfl_xor(core[jj][c], 1));
        core[jj][c] = fmaxf(core[jj][c], __shfl_xor(core[jj][c], 2));
        core[jj][c] = fmaxf(core[jj][c], __shfl_xor(core[jj][c], 4));
      }
#pragma unroll
    for (int jj = 0; jj < 4; ++jj) {
      float cv = core[jj][0];
#pragma unroll
      for (int c = 1; c < 8; ++c) cv = (io == c) ? core[jj][c] : cv;
      const unsigned short t3e =
          te3p[((size_t)(b * N) + j0 + jj) * N * CH + kbase + io];
      trif[jj * 512 + kl * 8 + io] =
          cv + t2j4[jj * 8 + io] + t3p[kbase + io] + b2f(t3e) + tgb[io];
    }
    __syncthreads();

    const int o = t & 127, rh = t >> 7;  // rh 0..3
    float wcol[8];
#pragma unroll
    for (int c = 0; c < 8; ++c) wcol[c] = wu3[c * 128 + o];
#pragma unroll 4
    for (int q = 0; q < 64; ++q) {
      const int row = q * 4 + rh;  // 0..255 = jj*64 + klr
      const int jj = row >> 6, klr = row & 63;
      const float4 f0 = *reinterpret_cast<const float4*>(&trif[row * 8]);
      const float4 f1 = *reinterpret_cast<const float4*>(&trif[row * 8 + 4]);
      float acc2 = f0.x * wcol[0] + f0.y * wcol[1] + f0.z * wcol[2] +
                   f0.w * wcol[3] + f1.x * wcol[4] + f1.y * wcol[5] +
                   f1.z * wcol[6] + f1.w * wcol[7];
      out_tri[((size_t)(b * N) + j0 + jj) * N * O +
              (size_t)(kh * 64 + klr) * O + o] = acc2;
    }
  }
}

// ---------------------------------------------------------------------------
// Kernel C: finalize msgs + ret (unchanged)
// ---------------------------------------------------------------------------
__global__ __launch_bounds__(256) void k_fin(
    const float* __restrict__ WU2, const float* __restrict__ ws,
    float* __restrict__ out_ret, float* __restrict__ out_msgs) {
  const int blk = blockIdx.x;
  const int b = blk >> 7, j = blk & 127;
  const int t = threadIdx.x;
  __shared__ float msgsrow[O];
  __shared__ float red[2][O];

  const float* part = ws + OFF_PART + ((size_t)(b * N) + j) * 4 * O;
  if (t < O) {
    const float m = fmaxf(fmaxf(part[t], part[O + t]),
                          fmaxf(part[2 * O + t], part[3 * O + t]));
    msgsrow[t] = m;
    out_msgs[((size_t)(b * N) + j) * O + t] = m;
  }
  __syncthreads();

  const int o = t & 127, h = t >> 7;
  float acc = 0.f;
#pragma unroll 8
  for (int p = h * 64; p < h * 64 + 64; ++p)
    acc += msgsrow[p] * WU2[(size_t)p * O + o];
  red[h][o] = acc;
  __syncthreads();
  if (t < O) {
    out_ret[((size_t)(b * N) + j) * O + t] =
        ws[OFF_ZU1 + ((size_t)(b * N) + j) * O + t] + red[0][t] + red[1][t];
  }
}

// ---------------------------------------------------------------------------
extern "C" void kernel_launch(void* const* d_in, const int* in_sizes, int n_in,
                              void* d_out, int out_size, void* d_ws,
                              size_t ws_size, hipStream_t stream) {
  const float* z    = (const float*)d_in[0];
  const float* e    = (const float*)d_in[1];
  const float* g    = (const float*)d_in[2];
  const void*  mmsk = d_in[4];
  const float* Wt1  = (const float*)d_in[5];
  const float* Wt2  = (const float*)d_in[6];
  const float* Wt3  = (const float*)d_in[7];
  const float* Wte1 = (const float*)d_in[8];
  const float* Wte2 = (const float*)d_in[9];
  const float* Wte3 = (const float*)d_in[10];
  const float* Wtg  = (const float*)d_in[11];
  const float* Wm1  = (const float*)d_in[12];
  const float* Wm2  = (const float*)d_in[13];
  const float* Wme  = (const float*)d_in[14];
  const float* Wmg  = (const float*)d_in[15];
  const float* Wmlp1= (const float*)d_in[16];
  const float* Wmlp2= (const float*)d_in[17];
  const float* WU1  = (const float*)d_in[18];
  const float* WU2  = (const float*)d_in[19];
  const float* WU3  = (const float*)d_in[20];

  float* ws = (float*)d_ws;
  float* out_ret  = (float*)d_out;
  float* out_msgs = out_ret + (size_t)B * N * O;
  float* out_tri  = out_msgs + (size_t)B * N * O;

  k_prep<<<1027, dim3(256), 0, stream>>>(z, g, e, Wt1, Wt2, Wt3, Wtg, Wm1, Wm2,
                                         Wmg, WU1, Wte1, Wte2, Wte3, Wme, Wmlp1,
                                         Wmlp2, ws);
  k_main<<<512, dim3(512), 0, stream>>>(e, mmsk, WU3, ws, ws, out_tri);
  k_fin<<<B * N, dim3(256), 0, stream>>>(WU2, ws, out_ret, out_msgs);
}

// Round 12
// 75.999 us; speedup vs baseline: 1.0501x; 1.0501x over previous
//
#include <hip/hip_runtime.h>
#include <hip/hip_bf16.h>
#include <cstdint>
#include <cstddef>

namespace {

constexpr int B = 4, N = 128, C = 256, E = 128, O = 128, CH = 8;
constexpr float NEGV = -1.0e9f;

// ---- workspace layout (in float units) ----
constexpr size_t SZ_TE_F  = (size_t)B * N * N * CH / 2;   // bf16 tensors
constexpr size_t OFF_TE1T = 0;                             // bf16 [b][j][i][c]
constexpr size_t OFF_TE2  = OFF_TE1T + SZ_TE_F;            // bf16 [b][i][k][c]
constexpr size_t OFF_TE3  = OFF_TE2 + SZ_TE_F;             // bf16 [b][j][k][c]
constexpr size_t OFF_M1   = OFF_TE3 + SZ_TE_F;             // f32 m1+mg [b][n][o]
constexpr size_t OFF_M2   = OFF_M1 + (size_t)B * N * O;
constexpr size_t OFF_ZU1  = OFF_M2 + (size_t)B * N * O;    // f32 [b][n][o]
constexpr size_t OFF_T1   = OFF_ZU1 + (size_t)B * N * O;   // f32 [b][n][c]
constexpr size_t OFF_T2   = OFF_T1 + (size_t)B * N * CH;
constexpr size_t OFF_T3   = OFF_T2 + (size_t)B * N * CH;
constexpr size_t OFF_TG   = OFF_T3 + (size_t)B * N * CH;   // f32 [b][c]
constexpr size_t OFF_WT   = OFF_TG + (size_t)B * CH;       // 3 x bf16[O][E]
constexpr size_t OFF_PART = OFF_WT + (size_t)3 * O * E / 2;  // f32 [b][j][8][o]

typedef __attribute__((ext_vector_type(4))) float f32x4;
typedef __attribute__((ext_vector_type(8))) short bf16x8;
typedef __attribute__((ext_vector_type(8))) unsigned short u16x8;
typedef __attribute__((ext_vector_type(4))) unsigned u32x4;

__device__ __forceinline__ unsigned short f2b(float f) {
  unsigned u = __float_as_uint(f);
  u = (u + 0x7fffu + ((u >> 16) & 1u)) >> 16;
  return (unsigned short)u;
}
__device__ __forceinline__ float b2f(unsigned short u) {
  return __uint_as_float((unsigned)u << 16);
}

} // namespace

// ---------------------------------------------------------------------------
// Kernel A (prep): fused te-MFMA [0,512) + pre [512,1024) + wprep [1024,1027)
// (unchanged from round 11)
// ---------------------------------------------------------------------------
__global__ __launch_bounds__(256) void k_prep(
    const float* __restrict__ z, const float* __restrict__ g,
    const float* __restrict__ e,
    const float* __restrict__ Wt1, const float* __restrict__ Wt2,
    const float* __restrict__ Wt3, const float* __restrict__ Wtg,
    const float* __restrict__ Wm1, const float* __restrict__ Wm2,
    const float* __restrict__ Wmg, const float* __restrict__ WU1,
    const float* __restrict__ Wte1, const float* __restrict__ Wte2,
    const float* __restrict__ Wte3,
    const float* __restrict__ Wme, const float* __restrict__ Wmlp1,
    const float* __restrict__ Wmlp2, float* __restrict__ ws) {
  __shared__ __align__(16) char smem[17408];
  const int blk = blockIdx.x;
  const int t = threadIdx.x;

  if (blk < 512) {
    unsigned short* wpack = (unsigned short*)(smem);            // [32][136]
    unsigned short* outl  = (unsigned short*)(smem + 8704);     // [128][32]
    unsigned short* te1T = (unsigned short*)(ws + OFF_TE1T);
    unsigned short* te2  = (unsigned short*)(ws + OFF_TE2);
    unsigned short* te3  = (unsigned short*)(ws + OFF_TE3);
    const int b = blk >> 7, i = blk & 127;

    for (int x = t; x < 3072; x += 256) {
      const int m = x >> 10, rem = x & 1023, k = rem >> 3, c = rem & 7;
      const float* W = (m == 0) ? Wte1 : ((m == 1) ? Wte2 : Wte3);
      const int row = m * 8 + c;
      wpack[row * 136 + k] = f2b(W[rem]);
    }
    for (int x = t; x < 1024; x += 256) {
      const int row = 24 + (x >> 7), col = x & 127;
      wpack[row * 136 + col] = 0;
    }
    __syncthreads();

    const float* erow = e + ((size_t)(b * N) + i) * N * E;
    const int lane = t & 63, wid = t >> 6;
    const int li = lane & 15, lk8 = (lane >> 4) * 8, lq4 = (lane >> 4) * 4;
    const int jt = wid & 1, ct = wid >> 1;
    const int c0 = ct * 16 + lq4;

    bf16x8 wf[4];
#pragma unroll
    for (int kt = 0; kt < 4; ++kt) {
      const int rw = ct * 16 + li;
      wf[kt] = *reinterpret_cast<const bf16x8*>(&wpack[rw * 136 + kt * 32 + lk8]);
    }

#pragma unroll 2
    for (int step = 0; step < 4; ++step) {
      const int jrow = step * 32 + jt * 16 + li;
      const float* er = erow + (size_t)jrow * E;
      float4 v[4][2];
#pragma unroll
      for (int kt = 0; kt < 4; ++kt) {
        v[kt][0] = *reinterpret_cast<const float4*>(&er[kt * 32 + lk8]);
        v[kt][1] = *reinterpret_cast<const float4*>(&er[kt * 32 + lk8 + 4]);
      }
      f32x4 acc = {0.f, 0.f, 0.f, 0.f};
#pragma unroll
      for (int kt = 0; kt < 4; ++kt) {
        u16x8 af;
        af[0] = f2b(v[kt][0].x); af[1] = f2b(v[kt][0].y);
        af[2] = f2b(v[kt][0].z); af[3] = f2b(v[kt][0].w);
        af[4] = f2b(v[kt][1].x); af[5] = f2b(v[kt][1].y);
        af[6] = f2b(v[kt][1].z); af[7] = f2b(v[kt][1].w);
        acc = __builtin_amdgcn_mfma_f32_16x16x32_bf16(
            wf[kt], (bf16x8)af, acc, 0, 0, 0);
      }
      if (c0 < 24) {
        ushort4 pk;
        pk.x = f2b(acc[0]); pk.y = f2b(acc[1]);
        pk.z = f2b(acc[2]); pk.w = f2b(acc[3]);
        *reinterpret_cast<ushort4*>(&outl[jrow * 32 + c0]) = pk;
      }
    }
    __syncthreads();
    for (int x = t; x < 384; x += 256) {
      const int m = x >> 7, j = x & 127;
      const u16x8 v = *reinterpret_cast<const u16x8*>(&outl[j * 32 + m * 8]);
      if (m == 0)
        *reinterpret_cast<u16x8*>(&te1T[(((size_t)(b * N) + j) * N + i) * CH]) = v;
      else if (m == 1)
        *reinterpret_cast<u16x8*>(&te2[(((size_t)(b * N) + i) * N + j) * CH]) = v;
      else
        *reinterpret_cast<u16x8*>(&te3[(((size_t)(b * N) + i) * N + j) * CH]) = v;
    }
  } else if (blk < 1024) {
    float* zrow = (float*)(smem);
    float* grow = (float*)(smem + 1024);
    const int bn = blk - 512;
    const int b = bn >> 7, n = bn & 127;

    for (int k = t; k < C; k += 256) zrow[k] = z[((size_t)(b * N) + n) * C + k];
    if (t < C / 2) grow[t] = g[(size_t)b * (C / 2) + t];
    __syncthreads();

    {
      const int o = t & 127;
      const float* W = (t < 128) ? Wm1 : Wm2;
      float acc = 0.f;
#pragma unroll 16
      for (int k = 0; k < C; ++k) acc += zrow[k] * W[(size_t)k * O + o];
      if (t < 128) {
        float mgacc = 0.f;
#pragma unroll 8
        for (int k = 0; k < C / 2; ++k) mgacc += grow[k] * Wmg[(size_t)k * O + o];
        acc += mgacc;
        ws[OFF_M1 + ((size_t)(b * N) + n) * O + o] = acc;
      } else {
        ws[OFF_M2 + ((size_t)(b * N) + n) * O + o] = acc;
      }
    }
    if (t < 128) {
      float acc = 0.f;
#pragma unroll 16
      for (int k = 0; k < C; ++k) acc += zrow[k] * WU1[(size_t)k * O + t];
      ws[OFF_ZU1 + ((size_t)(b * N) + n) * O + t] = acc;
    } else if (t < 152) {
      const int idx = t - 128;
      const int which = idx >> 3, c = idx & 7;
      const float* W = (which == 0) ? Wt1 : ((which == 1) ? Wt2 : Wt3);
      float acc = 0.f;
#pragma unroll 8
      for (int k = 0; k < C; ++k) acc += zrow[k] * W[(size_t)k * CH + c];
      const size_t off = (which == 0) ? OFF_T1 : ((which == 1) ? OFF_T2 : OFF_T3);
      ws[off + ((size_t)(b * N) + n) * CH + c] = acc;
    }
    if (n == 0 && t >= 152 && t < 160) {
      const int c = t - 152;
      float acc = 0.f;
      for (int k = 0; k < C / 2; ++k) acc += grow[k] * Wtg[(size_t)k * CH + c];
      ws[OFF_TG + (size_t)b * CH + c] = acc;
    }
  } else {
    const int which = blk - 1024;
    const float* W = (which == 0) ? Wme : ((which == 1) ? Wmlp1 : Wmlp2);
    unsigned short* dst = (unsigned short*)(ws + OFF_WT) + (size_t)which * O * E;
    for (int x = t; x < O * E; x += 256) {
      const int o = x >> 7, k = x & 127;
      dst[x] = f2b(W[(size_t)k * O + o]);
    }
  }
}

// ---------------------------------------------------------------------------
// Kernel B (main), 512 threads:
//  blocks [0,256): msgs REG-RESIDENT: block=(b, 2 j's); wave wid owns rows
//    16*wid..16*wid+15 through all 3 layers in registers. Layer transition is
//    a fixed lane permutation (pack bf16 + __shfl). Weights staged per-layer
//    to LDS. 5 barriers/block total. Per-wave partial max -> ws[PART][8].
//  blocks [256,512): tri (unchanged from round 11)
// ---------------------------------------------------------------------------
__global__ __launch_bounds__(512) void k_main(
    const float* __restrict__ e, const void* __restrict__ msk,
    const float* __restrict__ WU3, const float* __restrict__ ws_c,
    float* __restrict__ ws, float* __restrict__ out_tri) {
  __shared__ __align__(16) char smem[34816];
  const int blk = blockIdx.x;
  const int t = threadIdx.x;

  if (blk < 256) {
    // ===================== msgs branch (reg-resident) =====================
    unsigned short* lds_w = (unsigned short*)smem;  // [128][136] one layer
    const int b = blk >> 6, jp = blk & 63;
    const int j0 = jp * 2;
    const int lane = t & 63, wid = t >> 6;
    const int li = lane & 15, g = lane >> 4;
    const int i = wid * 16 + li;  // this lane's row (same for all g)

    // mask dtype sniff (wave-local, no LDS)
    int fmt;
    {
      const unsigned w = ((const unsigned*)msk)[lane];
      const float f = __uint_as_float(w);
      const unsigned long long bi = __ballot(w > 1u);
      const unsigned long long bfl = __ballot(!(f == 0.f || f == 1.f));
      fmt = (bi == 0ull) ? 0 : ((bfl == 0ull) ? 2 : 1);
    }
    int mkv0, mkv1;
    {
      const size_t ia = ((size_t)(b * N) + i) * N + j0;
      const size_t ib = ia + 1;
      if (fmt == 0) { mkv0 = ((const int*)msk)[ia] != 0; mkv1 = ((const int*)msk)[ib] != 0; }
      else if (fmt == 1) { mkv0 = ((const unsigned char*)msk)[ia] != 0; mkv1 = ((const unsigned char*)msk)[ib] != 0; }
      else { mkv0 = ((const float*)msk)[ia] != 0.f; mkv1 = ((const float*)msk)[ib] != 0.f; }
    }

    // m2 (j-invariant) -> registers
    float4 m2r[8];
#pragma unroll
    for (int ot = 0; ot < 8; ++ot)
      m2r[ot] = *reinterpret_cast<const float4*>(
          &ws_c[OFF_M2 + ((size_t)(b * N) + i) * O + ot * 16 + g * 4]);

    // layer-0 B-frags directly from e (both j's)
    bf16x8 bfrag[2][4];
#pragma unroll
    for (int jj = 0; jj < 2; ++jj)
#pragma unroll
      for (int kt = 0; kt < 4; ++kt) {
        const float* ep =
            &e[(((size_t)(b * N) + i) * N + j0 + jj) * E + kt * 32 + g * 8];
        const float4 v0 = *reinterpret_cast<const float4*>(ep);
        const float4 v1 = *reinterpret_cast<const float4*>(ep + 4);
        u16x8 af;
        af[0] = f2b(v0.x); af[1] = f2b(v0.y); af[2] = f2b(v0.z); af[3] = f2b(v0.w);
        af[4] = f2b(v1.x); af[5] = f2b(v1.y); af[6] = f2b(v1.z); af[7] = f2b(v1.w);
        bfrag[jj][kt] = (bf16x8)af;
      }

    f32x4 acc[2][8];
    const unsigned short* wts = (const unsigned short*)(ws_c + OFF_WT);

#define STAGE_W(L)                                                        \
  { const unsigned short* wl = wts + (size_t)(L)*O * E;                   \
    _Pragma("unroll") for (int x = 0; x < 4; ++x) {                       \
      const int idx = t + x * 512;                                        \
      const int row = idx >> 4, cg = idx & 15;                            \
      *reinterpret_cast<u16x8*>(&lds_w[row * 136 + cg * 8]) =             \
          *reinterpret_cast<const u16x8*>(&wl[row * 128 + cg * 8]);       \
    } }

#define MFMA_L()                                                          \
  _Pragma("unroll") for (int ot = 0; ot < 8; ++ot) {                      \
    acc[0][ot] = (f32x4){0.f, 0.f, 0.f, 0.f};                             \
    acc[1][ot] = (f32x4){0.f, 0.f, 0.f, 0.f};                             \
    _Pragma("unroll") for (int kt = 0; kt < 4; ++kt) {                    \
      const bf16x8 wf = *reinterpret_cast<const bf16x8*>(                 \
          &lds_w[(ot * 16 + li) * 136 + kt * 32 + g * 8]);                \
      acc[0][ot] = __builtin_amdgcn_mfma_f32_16x16x32_bf16(               \
          wf, bfrag[0][kt], acc[0][ot], 0, 0, 0);                         \
      acc[1][ot] = __builtin_amdgcn_mfma_f32_16x16x32_bf16(               \
          wf, bfrag[1][kt], acc[1][ot], 0, 0, 0);                         \
    } }

    // o->k lane redistribution: lane (g,li) builds next-layer k-frag from
    // acc of lanes src1=(2*(g&1))*16+li and src2=src1+16, at ot=2kt+(g>>1).
#define TRANSITION(jj)                                                    \
  { unsigned pk0[8], pk1[8];                                              \
    _Pragma("unroll") for (int ot = 0; ot < 8; ++ot) {                    \
      pk0[ot] = (unsigned)f2b(acc[jj][ot][0]) |                           \
                ((unsigned)f2b(acc[jj][ot][1]) << 16);                    \
      pk1[ot] = (unsigned)f2b(acc[jj][ot][2]) |                           \
                ((unsigned)f2b(acc[jj][ot][3]) << 16);                    \
    }                                                                     \
    const int src1 = ((lane >> 4) & 1) * 32 + li;                         \
    const int src2 = src1 + 16;                                           \
    const bool hi = lane >= 32;                                           \
    _Pragma("unroll") for (int kt = 0; kt < 4; ++kt) {                    \
      const unsigned a0 = __shfl(pk0[2 * kt], src1);                      \
      const unsigned b0 = __shfl(pk0[2 * kt + 1], src1);                  \
      const unsigned a1 = __shfl(pk1[2 * kt], src1);                      \
      const unsigned b1 = __shfl(pk1[2 * kt + 1], src1);                  \
      const unsigned a2 = __shfl(pk0[2 * kt], src2);                      \
      const unsigned b2 = __shfl(pk0[2 * kt + 1], src2);                  \
      const unsigned a3 = __shfl(pk1[2 * kt], src2);                      \
      const unsigned b3 = __shfl(pk1[2 * kt + 1], src2);                  \
      u32x4 q;                                                            \
      q.x = hi ? b0 : a0; q.y = hi ? b1 : a1;                             \
      q.z = hi ? b2 : a2; q.w = hi ? b3 : a3;                             \
      bfrag[jj][kt] = __builtin_bit_cast(bf16x8, q);                      \
    } }

    // ===== layer 0 =====
    STAGE_W(0);
    __syncthreads();
    MFMA_L();
#pragma unroll
    for (int jj = 0; jj < 2; ++jj) {
      const float mkf = (jj ? mkv1 : mkv0) ? 1.f : 0.f;
#pragma unroll
      for (int ot = 0; ot < 8; ++ot) {
        const float4 m1v = *reinterpret_cast<const float4*>(
            &ws_c[OFF_M1 + ((size_t)(b * N) + j0 + jj) * O + ot * 16 + g * 4]);
        acc[jj][ot][0] = fmaxf(acc[jj][ot][0] * mkf + m2r[ot].x + m1v.x, 0.f);
        acc[jj][ot][1] = fmaxf(acc[jj][ot][1] * mkf + m2r[ot].y + m1v.y, 0.f);
        acc[jj][ot][2] = fmaxf(acc[jj][ot][2] * mkf + m2r[ot].z + m1v.z, 0.f);
        acc[jj][ot][3] = fmaxf(acc[jj][ot][3] * mkf + m2r[ot].w + m1v.w, 0.f);
      }
    }
    TRANSITION(0);
    TRANSITION(1);

    // ===== layer 1 =====
    __syncthreads();
    STAGE_W(1);
    __syncthreads();
    MFMA_L();
#pragma unroll
    for (int jj = 0; jj < 2; ++jj)
#pragma unroll
      for (int ot = 0; ot < 8; ++ot) {
        acc[jj][ot][0] = fmaxf(acc[jj][ot][0], 0.f);
        acc[jj][ot][1] = fmaxf(acc[jj][ot][1], 0.f);
        acc[jj][ot][2] = fmaxf(acc[jj][ot][2], 0.f);
        acc[jj][ot][3] = fmaxf(acc[jj][ot][3], 0.f);
      }
    TRANSITION(0);
    TRANSITION(1);

    // ===== layer 2 =====
    __syncthreads();
    STAGE_W(2);
    __syncthreads();
    MFMA_L();
    // masked max over this wave's 16 rows (reduce across li within g-group)
#pragma unroll
    for (int jj = 0; jj < 2; ++jj) {
      const bool mm = (jj ? mkv1 : mkv0) != 0;
      float* part =
          ws + OFF_PART + (((size_t)(b * N) + j0 + jj) * 8 + wid) * O;
#pragma unroll
      for (int ot = 0; ot < 8; ++ot) {
        float v0 = mm ? acc[jj][ot][0] : NEGV;
        float v1 = mm ? acc[jj][ot][1] : NEGV;
        float v2 = mm ? acc[jj][ot][2] : NEGV;
        float v3 = mm ? acc[jj][ot][3] : NEGV;
#pragma unroll
        for (int off = 1; off < 16; off <<= 1) {
          v0 = fmaxf(v0, __shfl_xor(v0, off));
          v1 = fmaxf(v1, __shfl_xor(v1, off));
          v2 = fmaxf(v2, __shfl_xor(v2, off));
          v3 = fmaxf(v3, __shfl_xor(v3, off));
        }
        if (li == 0)
          *reinterpret_cast<float4*>(&part[ot * 16 + g * 4]) =
              make_float4(v0, v1, v2, v3);
      }
    }
#undef STAGE_W
#undef MFMA_L
#undef TRANSITION
  } else {
    // ============== tri branch: (b, kh, jt->4 j's), 512 threads ==============
    float* A4   = (float*)(smem);            // [4][128][8] f32
    float* wu3  = (float*)(smem + 16384);    // [8][128] f32
    float* trif = (float*)(smem + 20480);    // [4][64][8] f32
    float* t2j4 = (float*)(smem + 28672);    // [4][8]
    float* tgb  = (float*)(smem + 28800);    // [8]
    const int blk2 = blk - 256;
    const int kh = blk2 & 1, jt = (blk2 >> 1) & 31, b = blk2 >> 6;
    const int j0 = jt * 4;

    const unsigned short* te1T = (const unsigned short*)(ws_c + OFF_TE1T);
    const unsigned short* te2p =
        (const unsigned short*)(ws_c + OFF_TE2) + (size_t)b * N * N * CH;
    const unsigned short* te3p = (const unsigned short*)(ws_c + OFF_TE3);
    const float* t1p = ws_c + OFF_T1 + (size_t)b * N * CH;
    const float* t3p = ws_c + OFF_T3 + (size_t)b * N * CH;

    {
      const int idx8 = t * 8;
      const int jj = idx8 >> 10, i = (idx8 & 1023) >> 3;
      const u16x8 tv = *reinterpret_cast<const u16x8*>(
          &te1T[((size_t)(b * N) + j0 + jj) * N * CH + i * 8]);
      const float4 t1a = *reinterpret_cast<const float4*>(&t1p[i * 8]);
      const float4 t1b = *reinterpret_cast<const float4*>(&t1p[i * 8 + 4]);
      float4 av0, av1;
      av0.x = b2f(tv[0]) + t1a.x; av0.y = b2f(tv[1]) + t1a.y;
      av0.z = b2f(tv[2]) + t1a.z; av0.w = b2f(tv[3]) + t1a.w;
      av1.x = b2f(tv[4]) + t1b.x; av1.y = b2f(tv[5]) + t1b.y;
      av1.z = b2f(tv[6]) + t1b.z; av1.w = b2f(tv[7]) + t1b.w;
      *reinterpret_cast<float4*>(&A4[idx8]) = av0;
      *reinterpret_cast<float4*>(&A4[idx8 + 4]) = av1;
    }
    if (t < 256)
      *reinterpret_cast<float4*>(&wu3[t * 4]) =
          *reinterpret_cast<const float4*>(&WU3[t * 4]);
    if (t < 32)
      t2j4[t] = ws_c[OFF_T2 + ((size_t)(b * N) + j0 + (t >> 3)) * CH + (t & 7)];
    if (t < 8) tgb[t] = ws_c[OFF_TG + (size_t)b * CH + t];
    __syncthreads();

    const int io = t & 7, kl = t >> 3;  // kl 0..63
    const int kg = kh * 64 + kl;
    const size_t kbase = (size_t)kg * CH;
    float core[4][8];
#pragma unroll
    for (int jj = 0; jj < 4; ++jj)
#pragma unroll
      for (int c = 0; c < 8; ++c) core[jj][c] = -3.0e38f;

#pragma unroll 2
    for (int i0 = 0; i0 < N; i0 += 8) {
      const int i = i0 + io;
      const u16x8 rv =
          *reinterpret_cast<const u16x8*>(&te2p[(size_t)i * N * CH + kbase]);
      float r[8];
#pragma unroll
      for (int c = 0; c < 8; ++c) r[c] = b2f(rv[c]);
#pragma unroll
      for (int jj = 0; jj < 4; ++jj) {
        const float4 a0 = *reinterpret_cast<const float4*>(&A4[jj * 1024 + i * 8]);
        const float4 a1 = *reinterpret_cast<const float4*>(&A4[jj * 1024 + i * 8 + 4]);
        core[jj][0] = fmaxf(core[jj][0], a0.x + r[0]);
        core[jj][1] = fmaxf(core[jj][1], a0.y + r[1]);
        core[jj][2] = fmaxf(core[jj][2], a0.z + r[2]);
        core[jj][3] = fmaxf(core[jj][3], a0.w + r[3]);
        core[jj][4] = fmaxf(core[jj][4], a1.x + r[4]);
        core[jj][5] = fmaxf(core[jj][5], a1.y + r[5]);
        core[jj][6] = fmaxf(core[jj][6], a1.z + r[6]);
        core[jj][7] = fmaxf(core[jj][7], a1.w + r[7]);
      }
    }
#pragma unroll
    for (int jj = 0; jj < 4; ++jj)
#pragma unroll
      for (int c = 0; c < 8; ++c) {
        core[jj][c] = fmaxf(core[jj][c], __shfl_xor(core[jj][c], 1));
        core[jj][c] = fmaxf(core[jj][c], __shfl_xor(core[jj][c], 2));
        core[jj][c] = fmaxf(core[jj][c], __shfl_xor(core[jj][c], 4));
      }
#pragma unroll
    for (int jj = 0; jj < 4; ++jj) {
      float cv = core[jj][0];
#pragma unroll
      for (int c = 1; c < 8; ++c) cv = (io == c) ? core[jj][c] : cv;
      const unsigned short t3e =
          te3p[((size_t)(b * N) + j0 + jj) * N * CH + kbase + io];
      trif[jj * 512 + kl * 8 + io] =
          cv + t2j4[jj * 8 + io] + t3p[kbase + io] + b2f(t3e) + tgb[io];
    }
    __syncthreads();

    const int o = t & 127, rh = t >> 7;  // rh 0..3
    float wcol[8];
#pragma unroll
    for (int c = 0; c < 8; ++c) wcol[c] = wu3[c * 128 + o];
#pragma unroll 4
    for (int q = 0; q < 64; ++q) {
      const int row = q * 4 + rh;  // 0..255 = jj*64 + klr
      const int jj = row >> 6, klr = row & 63;
      const float4 f0 = *reinterpret_cast<const float4*>(&trif[row * 8]);
      const float4 f1 = *reinterpret_cast<const float4*>(&trif[row * 8 + 4]);
      float acc2 = f0.x * wcol[0] + f0.y * wcol[1] + f0.z * wcol[2] +
                   f0.w * wcol[3] + f1.x * wcol[4] + f1.y * wcol[5] +
                   f1.z * wcol[6] + f1.w * wcol[7];
      out_tri[((size_t)(b * N) + j0 + jj) * N * O +
              (size_t)(kh * 64 + klr) * O + o] = acc2;
    }
  }
}

// ---------------------------------------------------------------------------
// Kernel C: finalize msgs (8-way partials) + ret
// ---------------------------------------------------------------------------
__global__ __launch_bounds__(256) void k_fin(
    const float* __restrict__ WU2, const float* __restrict__ ws,
    float* __restrict__ out_ret, float* __restrict__ out_msgs) {
  const int blk = blockIdx.x;
  const int b = blk >> 7, j = blk & 127;
  const int t = threadIdx.x;
  __shared__ float msgsrow[O];
  __shared__ float red[2][O];

  const float* part = ws + OFF_PART + ((size_t)(b * N) + j) * 8 * O;
  if (t < O) {
    float m = part[t];
#pragma unroll
    for (int p = 1; p < 8; ++p) m = fmaxf(m, part[p * O + t]);
    msgsrow[t] = m;
    out_msgs[((size_t)(b * N) + j) * O + t] = m;
  }
  __syncthreads();

  const int o = t & 127, h = t >> 7;
  float acc = 0.f;
#pragma unroll 8
  for (int p = h * 64; p < h * 64 + 64; ++p)
    acc += msgsrow[p] * WU2[(size_t)p * O + o];
  red[h][o] = acc;
  __syncthreads();
  if (t < O) {
    out_ret[((size_t)(b * N) + j) * O + t] =
        ws[OFF_ZU1 + ((size_t)(b * N) + j) * O + t] + red[0][t] + red[1][t];
  }
}

// ---------------------------------------------------------------------------
extern "C" void kernel_launch(void* const* d_in, const int* in_sizes, int n_in,
                              void* d_out, int out_size, void* d_ws,
                              size_t ws_size, hipStream_t stream) {
  const float* z    = (const float*)d_in[0];
  const float* e    = (const float*)d_in[1];
  const float* g    = (const float*)d_in[2];
  const void*  mmsk = d_in[4];
  const float* Wt1  = (const float*)d_in[5];
  const float* Wt2  = (const float*)d_in[6];
  const float* Wt3  = (const float*)d_in[7];
  const float* Wte1 = (const float*)d_in[8];
  const float* Wte2 = (const float*)d_in[9];
  const float* Wte3 = (const float*)d_in[10];
  const float* Wtg  = (const float*)d_in[11];
  const float* Wm1  = (const float*)d_in[12];
  const float* Wm2  = (const float*)d_in[13];
  const float* Wme  = (const float*)d_in[14];
  const float* Wmg  = (const float*)d_in[15];
  const float* Wmlp1= (const float*)d_in[16];
  const float* Wmlp2= (const float*)d_in[17];
  const float* WU1  = (const float*)d_in[18];
  const float* WU2  = (const float*)d_in[19];
  const float* WU3  = (const float*)d_in[20];

  float* ws = (float*)d_ws;
  float* out_ret  = (float*)d_out;
  float* out_msgs = out_ret + (size_t)B * N * O;
  float* out_tri  = out_msgs + (size_t)B * N * O;

  k_prep<<<1027, dim3(256), 0, stream>>>(z, g, e, Wt1, Wt2, Wt3, Wtg, Wm1, Wm2,
                                         Wmg, WU1, Wte1, Wte2, Wte3, Wme, Wmlp1,
                                         Wmlp2, ws);
  k_main<<<512, dim3(512), 0, stream>>>(e, mmsk, WU3, ws, ws, out_tri);
  k_fin<<<B * N, dim3(256), 0, stream>>>(WU2, ws, out_ret, out_msgs);
}